// Round 15
// baseline (232.676 us; speedup 1.0000x reference)
//
#include <hip/hip_runtime.h>

// Problem constants: N=5, B=16, H=W=384, J=17
#define NF 5
#define NB 16
#define NH 384
#define NW 384
#define NJ 17
#define HW (NH * NW)
#define PW (NW + 3)                   // padded cols: x = -1 .. 385
#define PH (NH + 3)
#define PHW (PH * PW)                 // 149769
#define NPIX (NB * HW)                // 2,359,296
#define PACK_TOTAL (NB * PHW)         // 2,396,304
#define WROWS 12
#define WSIZE (WROWS * PW)            // 4644 u32 = 18.6 KB LDS
#define SBLOCKS (NB * NH)             // 6144 blocks of 512 threads
#define UNSUP1_BLOCKS ((NF * NB * HW) / 256) // 46080 (fallback)

// fast charbonnier: (x^2 + 1e-18)^0.25 via raw v_sqrt_f32 (~1 ulp; threshold 2% rel)
__device__ __forceinline__ float charb(float x) {
    return __builtin_amdgcn_sqrtf(__builtin_amdgcn_sqrtf(fmaf(x, x, 1e-18f)));
}
// RGB in [0,1) -> 11/11/10-bit fixed point in one u32 (abs err <= 4.9e-4)
__device__ __forceinline__ unsigned int packrgb(float r, float g, float b) {
    unsigned int er = (unsigned int)fmaf(r, 2047.f, 0.5f);
    unsigned int eg = (unsigned int)fmaf(g, 2047.f, 0.5f);
    unsigned int eb = (unsigned int)fmaf(b, 1023.f, 0.5f);
    return er | (eg << 11) | (eb << 22);
}
__device__ __forceinline__ float upk_r(unsigned int u) {
    return (float)(u & 2047u) * (1.f / 2047.f);
}
__device__ __forceinline__ float upk_g(unsigned int u) {
    return (float)((u >> 11) & 2047u) * (1.f / 2047.f);
}
__device__ __forceinline__ float upk_b(unsigned int u) {
    return (float)(u >> 22) * (1.f / 1023.f);
}

// ws layout (bytes):
//   [0..63]   float ws[0]=sup_sum, ws[1]=denom
//   [64 ..)                uint packed1[PACK_TOTAL]  (frm1 padded, 11/11/10 RGB)
//   [+PACK_TOTAL*4 ..)     uint packed0[NPIX]        (frm0, 11/11/10 RGB)
//   [+NPIX*4 ..)           float partials[SBLOCKS]
// fallback (no pack): partials at ws+16 floats

__global__ __launch_bounds__(256)
void repack_kp_kernel(const float* __restrict__ frm1, const float* __restrict__ frm0,
                      const float* __restrict__ kps, const float* __restrict__ pf,
                      float* __restrict__ ws, unsigned int* __restrict__ packed1,
                      unsigned int* __restrict__ packed0, int do_pack) {
    int g = blockIdx.x * 256 + threadIdx.x;
    if (do_pack) {
        if (g < PACK_TOTAL) {
            int b = g / PHW;
            int r = g - b * PHW;
            int py = r / PW;
            int px = r - py * PW;
            int x = px - 1, y = py - 1;
            unsigned int v = 0u;
            if (x >= 0 && x < NW && y >= 0 && y < NH) {
                const float* s = frm1 + (size_t)b * 3 * HW + y * NW + x;
                v = packrgb(s[0], s[HW], s[2 * HW]);
            }
            packed1[g] = v;
        }
        if (g < NPIX) {
            int b = g / HW;
            int o = g - b * HW;
            const float* s = frm0 + (size_t)b * 3 * HW + o;
            packed0[g] = packrgb(s[0], s[HW], s[2 * HW]);
        }
    }
    if (blockIdx.x == 0) {
        int t = threadIdx.x;
        // ---- keypoint supervised loss (sparse: <= 272 points, fp32 exact) ----
        __shared__ int cnt;
        __shared__ int ebase[NB * NJ];
        __shared__ float edx[NB * NJ], edy[NB * NJ];
        if (t == 0) cnt = 0;
        __syncthreads();
        for (int q = t; q < NB * NJ; q += 256) {
            int b = q / NJ, j = q - b * NJ;
            const float* k0 = kps + ((b * 2 + 0) * NJ + j) * 2;
            const float* k1 = kps + ((b * 2 + 1) * NJ + j) * 2;
            float x0 = k0[0], y0 = k0[1], x1 = k1[0], y1 = k1[1];
            bool valid = x0 >= 0.f && y0 >= 0.f && x1 >= 0.f && y1 >= 0.f &&
                         x0 < (float)NW && y0 < (float)NH &&
                         x1 < (float)NW && y1 < (float)NH;
            float dx = x1 - x0, dy = y1 - y0;
            if (valid && (dx != 0.f || dy != 0.f)) {
                int s = atomicAdd(&cnt, 1);
                ebase[s] = (b * 2) * HW + (int)floorf(y0) * NW + (int)floorf(x0);
                edx[s] = dx; edy[s] = dy;
            }
        }
        __syncthreads();
        int n = cnt;
        float local = 0.f;
        for (int q = t; q < n * NF; q += 256) {
            int e = q / NF, i = q - e * NF;
            float wt = (i == 0) ? 0.4096f : (i == 1) ? 0.512f :
                       (i == 2) ? 0.64f  : (i == 3) ? 0.8f   : 1.0f;
            int off = ebase[e] + i * (NB * 2 * HW);
            float ex = pf[off] - edx[e];
            float ey = pf[off + HW] - edy[e];
            local += wt * sqrtf(fmaf(ex, ex, ey * ey));
        }
        for (int o = 32; o > 0; o >>= 1) local += __shfl_down(local, o, 64);
        __shared__ float ssum[4];
        int lane = t & 63, wid = t >> 6;
        if (lane == 0) ssum[wid] = local;
        __syncthreads();
        if (t == 0) {
            ws[0] = ssum[0] + ssum[1] + ssum[2] + ssum[3];
            ws[1] = (float)n;
        }
    }
}

// Block = (b, h): 512 threads = 5 levels x 96 w4-groups (480 compute) + stagers.
// Stages 12 padded frm1 rows [lo, lo+11] (full width) into LDS; taps read LDS
// (ds_read_b32, ~2-way conflicts) instead of ~280 divergent L1 cachelines/wave
// (the measured bottleneck of rounds 13-14). Rare out-of-window taps (~1.2%/px,
// |fy|>5) take the old global path, exec-masked. frm0 uint4 now read once per
// 5 levels (same block). No atomics/fences (round-5 lesson).
__global__ __launch_bounds__(512, 8)
void unsup_stage_kernel(const float* __restrict__ pf,
                        const unsigned int* __restrict__ packed1,
                        const unsigned int* __restrict__ packed0,
                        float* __restrict__ partials) {
    __shared__ unsigned int win[WSIZE];
    const int t = threadIdx.x;
    const int blk = blockIdx.x;
    const int h = blk % NH;       // consecutive blocks = consecutive h: windows
    const int b = blk / NH;       // overlap 11/12 rows -> L2/L3 reuse of staging
    const int lo = min(max(h - 5, 0), PH - WROWS);   // window base padded row

    const unsigned int* pk = packed1 + (size_t)b * PHW;
    for (int s = t; s < WSIZE; s += 512) win[s] = pk[lo * PW + s];
    __syncthreads();

    float local = 0.f;
    if (t < 480) {
        const int w4 = t % 96;
        const int i = t / 96;
        const int w0 = w4 * 4;
        const int off = h * NW + w0;
        const float SC = (float)(NW - 1) / (float)NW;

        const uint4 f0 = *reinterpret_cast<const uint4*>(packed0 + (size_t)b * HW + off);

        const float* fb = pf + (size_t)((i * NB + b) * 2) * HW + off;
        const float4 fx4 = *(const float4*)fb;
        const float4 fy4 = *(const float4*)(fb + HW);
        float4 dnx4 = make_float4(0.f, 0.f, 0.f, 0.f);
        float4 dny4 = make_float4(0.f, 0.f, 0.f, 0.f);
        if (h < NH - 1) {
            dnx4 = *(const float4*)(fb + NW);
            dny4 = *(const float4*)(fb + NW + HW);
        }
        float rtx = 0.f, rty = 0.f;
        if (w0 + 4 < NW) { rtx = fb[4]; rty = fb[HW + 4]; }

        const float fxa[4] = {fx4.x, fx4.y, fx4.z, fx4.w};
        const float fya[4] = {fy4.x, fy4.y, fy4.z, fy4.w};
        const float rxa[4] = {fx4.y, fx4.z, fx4.w, rtx};
        const float rya[4] = {fy4.y, fy4.z, fy4.w, rty};
        const float dnxa[4] = {dnx4.x, dnx4.y, dnx4.z, dnx4.w};
        const float dnya[4] = {dny4.x, dny4.y, dny4.z, dny4.w};
        const unsigned int f0a[4] = {f0.x, f0.y, f0.z, f0.w};

        float smooth = 0.f, phot = 0.f;
#pragma unroll
        for (int k = 0; k < 4; ++k) {
            smooth += charb(fxa[k] - dnxa[k]) + charb(fya[k] - dnya[k]) +
                      charb(fxa[k] - rxa[k]) + charb(fya[k] - rya[k]);

            float xp = (fxa[k] + (float)(w0 + k)) * SC;
            float yp = (fya[k] + (float)h) * SC;
            xp = fminf(fmaxf(xp, -1.0f), 384.0f);
            yp = fminf(fmaxf(yp, -1.0f), 384.0f);
            float x0f = floorf(xp), y0f = floorf(yp);
            float wx1 = xp - x0f, wx0 = 1.f - wx1;
            float wy1 = yp - y0f, wy0 = 1.f - wy1;
            int px0 = (int)x0f + 1;            // padded col in [0, 385]
            int py0 = (int)y0f + 1;            // padded row in [0, 385]
            int wr = py0 - lo;
            unsigned int t00, t10, t01, t11;
            if ((unsigned)wr <= (unsigned)(WROWS - 2)) {   // rows wr, wr+1 in window
                int l = wr * PW + px0;
                t00 = win[l];
                t10 = win[l + 1];
                t01 = win[l + PW];
                t11 = win[l + PW + 1];
            } else {                                       // rare tail: global
                int g = py0 * PW + px0;
                t00 = pk[g];
                t10 = pk[g + 1];
                t01 = pk[g + PW];
                t11 = pk[g + PW + 1];
            }
            float w00 = wx0 * wy0, w10 = wx1 * wy0, w01 = wx0 * wy1, w11 = wx1 * wy1;
            float s0 = w00 * upk_r(t00) + w10 * upk_r(t10) +
                       w01 * upk_r(t01) + w11 * upk_r(t11);
            float s1 = w00 * upk_g(t00) + w10 * upk_g(t10) +
                       w01 * upk_g(t01) + w11 * upk_g(t11);
            float s2 = w00 * upk_b(t00) + w10 * upk_b(t10) +
                       w01 * upk_b(t01) + w11 * upk_b(t11);
            phot += charb(s0 - upk_r(f0a[k])) + charb(s1 - upk_g(f0a[k])) +
                    charb(s2 - upk_b(f0a[k]));
        }
        float wt = (i == 0) ? 0.4096f : (i == 1) ? 0.512f :
                   (i == 2) ? 0.64f  : (i == 3) ? 0.8f   : 1.0f;
        local = wt * fmaf(phot, (1.f / 3.f), smooth * 0.5f);
    }

    // block reduce (512 threads = 8 waves) -> per-block partial (no atomics)
    for (int o = 32; o > 0; o >>= 1) local += __shfl_down(local, o, 64);
    __shared__ float ssum[8];
    int lane = t & 63, wid = t >> 6;
    if (lane == 0) ssum[wid] = local;
    __syncthreads();
    if (t == 0) {
        float s = 0.f;
        #pragma unroll
        for (int k = 0; k < 8; ++k) s += ssum[k];
        partials[blockIdx.x] = s;
    }
}

// Fallback (ws too small): planar single-item kernel, fp32 exact
__global__ __launch_bounds__(256, 8)
void unsup1_kernel(const float* __restrict__ pf, const float* __restrict__ frm0,
                   const float* __restrict__ frm1, float* __restrict__ partials) {
    const int idx = blockIdx.x * 256 + threadIdx.x;
    const int w = idx % NW;
    int q = idx / NW;
    const int i = q % NF;
    q = q / NF;
    const int b = q & (NB - 1);
    const int h = q >> 4;
    const int off = h * NW + w;
    const float SC = (float)(NW - 1) / (float)NW;
    const float* f0b = frm0 + b * 3 * HW + off;
    const float c0 = f0b[0], c1 = f0b[HW], c2 = f0b[2 * HW];
    const float* fb = pf + (size_t)((i * NB + b) * 2) * HW + off;
    const float fx = fb[0], fy = fb[HW];
    float dnx = 0.f, dny = 0.f, rtx = 0.f, rty = 0.f;
    if (h < NH - 1) { dnx = fb[NW]; dny = fb[NW + HW]; }
    if (w < NW - 1) { rtx = fb[1];  rty = fb[HW + 1]; }
    float smooth = charb(fx - dnx) + charb(fy - dny) + charb(fx - rtx) + charb(fy - rty);
    float xp = (fx + (float)w) * SC, yp = (fy + (float)h) * SC;
    float x0f = floorf(xp), y0f = floorf(yp);
    float wx1 = xp - x0f, wx0 = 1.f - wx1, wy1 = yp - y0f, wy0 = 1.f - wy1;
    bool vx0 = (x0f >= 0.f) && (x0f <= (float)(NW - 1));
    bool vx1 = (x0f >= -1.f) && (x0f <= (float)(NW - 2));
    bool vy0 = (y0f >= 0.f) && (y0f <= (float)(NH - 1));
    bool vy1 = (y0f >= -1.f) && (y0f <= (float)(NH - 2));
    float m00 = (vx0 && vy0) ? wx0 * wy0 : 0.f;
    float m10 = (vx1 && vy0) ? wx1 * wy0 : 0.f;
    float m01 = (vx0 && vy1) ? wx0 * wy1 : 0.f;
    float m11 = (vx1 && vy1) ? wx1 * wy1 : 0.f;
    int x0i = min(max((int)x0f, 0), NW - 1);
    int y0i = min(max((int)y0f, 0), NH - 1);
    int x1i = min(x0i + 1, NW - 1);
    int y1i = min(y0i + 1, NH - 1);
    const float* img = frm1 + b * 3 * HW;
    int i00 = y0i * NW + x0i, i10 = y0i * NW + x1i;
    int i01 = y1i * NW + x0i, i11 = y1i * NW + x1i;
    float s0 = m00 * img[i00] + m10 * img[i10] + m01 * img[i01] + m11 * img[i11];
    float s1 = m00 * img[HW + i00] + m10 * img[HW + i10] + m01 * img[HW + i01] + m11 * img[HW + i11];
    float s2 = m00 * img[2 * HW + i00] + m10 * img[2 * HW + i10] + m01 * img[2 * HW + i01] + m11 * img[2 * HW + i11];
    float phot = charb(s0 - c0) + charb(s1 - c1) + charb(s2 - c2);
    float wt = (i == 0) ? 0.4096f : (i == 1) ? 0.512f :
               (i == 2) ? 0.64f  : (i == 3) ? 0.8f   : 1.0f;
    float local = wt * fmaf(phot, (1.f / 3.f), smooth * 0.5f);
    for (int o = 32; o > 0; o >>= 1) local += __shfl_down(local, o, 64);
    __shared__ float ssum[4];
    int lane = threadIdx.x & 63, wid = threadIdx.x >> 6;
    if (lane == 0) ssum[wid] = local;
    __syncthreads();
    if (threadIdx.x == 0) partials[blockIdx.x] = ssum[0] + ssum[1] + ssum[2] + ssum[3];
}

__global__ __launch_bounds__(1024)
void final_kernel(const float* __restrict__ ws, const float* __restrict__ partials,
                  float* __restrict__ out, int nparts) {
    float local = 0.f;
    for (int q = threadIdx.x; q < nparts; q += 1024) local += partials[q];
    for (int o = 32; o > 0; o >>= 1) local += __shfl_down(local, o, 64);
    __shared__ float ssum[16];
    int lane = threadIdx.x & 63, wid = threadIdx.x >> 6;
    if (lane == 0) ssum[wid] = local;
    __syncthreads();
    if (threadIdx.x == 0) {
        float uns = 0.f;
        #pragma unroll
        for (int k = 0; k < 16; ++k) uns += ssum[k];
        float denom = fmaxf(ws[1], 1.f);
        out[0] = uns * (1.f / (float)NB) + ws[0] / denom;
    }
}

extern "C" void kernel_launch(void* const* d_in, const int* in_sizes, int n_in,
                              void* d_out, int out_size, void* d_ws, size_t ws_size,
                              hipStream_t stream) {
    const float* pf   = (const float*)d_in[0];  // (5,16,2,384,384)
    const float* kps  = (const float*)d_in[1];  // (16,2,17,2)
    const float* frm0 = (const float*)d_in[2];  // (16,3,384,384)
    const float* frm1 = (const float*)d_in[3];  // (16,3,384,384)
    float* out = (float*)d_out;
    float* ws  = (float*)d_ws;

    char* base = (char*)d_ws;
    unsigned int* packed1 = (unsigned int*)(base + 64);
    unsigned int* packed0 = (unsigned int*)(base + 64 + (size_t)PACK_TOTAL * 4);
    float* partialsS = (float*)(base + 64 + (size_t)PACK_TOTAL * 4 + (size_t)NPIX * 4);

    const size_t need = 64 + (size_t)PACK_TOTAL * 4 + (size_t)NPIX * 4 +
                        (size_t)SBLOCKS * 4;
    if (ws_size >= need) {
        repack_kp_kernel<<<(PACK_TOTAL + 255) / 256, 256, 0, stream>>>(
            frm1, frm0, kps, pf, ws, packed1, packed0, 1);
        unsup_stage_kernel<<<SBLOCKS, 512, 0, stream>>>(pf, packed1, packed0, partialsS);
        final_kernel<<<1, 1024, 0, stream>>>(ws, partialsS, out, SBLOCKS);
    } else {
        float* partials1 = ws + 16;
        repack_kp_kernel<<<1, 256, 0, stream>>>(frm1, frm0, kps, pf, ws,
                                                packed1, packed0, 0);
        unsup1_kernel<<<UNSUP1_BLOCKS, 256, 0, stream>>>(pf, frm0, frm1, partials1);
        final_kernel<<<1, 1024, 0, stream>>>(ws, partials1, out, UNSUP1_BLOCKS);
    }
}